// Round 2
// baseline (1548.786 us; speedup 1.0000x reference)
//
#include <hip/hip_runtime.h>
#include <hip/hip_fp16.h>

#define D_FEAT     128
#define SCAN_B     1024
#define HBINS      16000     // node bins per LDS histogram pass (64 KB)
#define HSLICES    64        // edge slices for out-degree histogram
#define BUCKET_BITS 7
#define BUCKET_SZ  128       // dst nodes per bucket (LDS accumulator tile)
#define S_BIN      256       // edge slices for bucket binning
#define NB_MAX     1024      // max buckets supported (131072 nodes)

typedef float f32x4 __attribute__((ext_vector_type(4)));

// --- 1. out-degree histogram, LDS-privatized (no global atomics) ---
__global__ void hist_kernel(const int* __restrict__ src, int* __restrict__ part,
                            int n_edges, int n_nodes, int slice_len) {
    __shared__ int bins[HBINS];
    int s = blockIdx.x % HSLICES;
    int r = blockIdx.x / HSLICES;
    int lo = r * HBINS;
    int nb = n_nodes - lo; if (nb > HBINS) nb = HBINS;
    for (int i = threadIdx.x; i < nb; i += blockDim.x) bins[i] = 0;
    __syncthreads();
    int beg = s * slice_len;
    int end = beg + slice_len; if (end > n_edges) end = n_edges;
    for (int i = beg + threadIdx.x; i < end; i += blockDim.x) {
        unsigned int u = (unsigned int)(src[i] - lo);
        if (u < (unsigned int)nb) atomicAdd(&bins[u], 1);
    }
    __syncthreads();
    int* dp = part + (size_t)s * n_nodes + lo;
    for (int i = threadIdx.x; i < nb; i += blockDim.x) dp[i] = bins[i];
}

// --- 2. merge partials -> norm_l = rsqrt(max(deg_o,1)) ---
__global__ void merge_kernel(const int* __restrict__ part, float* __restrict__ norm_l,
                             int n_nodes) {
    int i = blockIdx.x * blockDim.x + threadIdx.x;
    if (i >= n_nodes) return;
    int sum = 0;
    #pragma unroll 8
    for (int s = 0; s < HSLICES; s++) sum += part[(size_t)s * n_nodes + i];
    if (sum < 1) sum = 1;
    norm_l[i] = rsqrtf((float)sum);
}

// --- 3. per-slice bucket histogram of dst -> partb[b*S_BIN + s] (no global atomics) ---
__global__ void binhist_kernel(const int* __restrict__ dst, int* __restrict__ partb,
                               int n_edges, int nb, int slice_len) {
    __shared__ int hist[NB_MAX];
    int s = blockIdx.x;
    for (int i = threadIdx.x; i < nb; i += blockDim.x) hist[i] = 0;
    __syncthreads();
    int beg = s * slice_len;
    int end = beg + slice_len; if (end > n_edges) end = n_edges;
    for (int i = beg + threadIdx.x; i < end; i += blockDim.x)
        atomicAdd(&hist[dst[i] >> BUCKET_BITS], 1);
    __syncthreads();
    for (int b = threadIdx.x; b < nb; b += blockDim.x)
        partb[(size_t)b * S_BIN + s] = hist[b];
}

// --- 4a. per-block exclusive scan, block totals to bsum ---
__global__ __launch_bounds__(SCAN_B) void scan1_kernel(const int* __restrict__ in,
        int* __restrict__ off, int* __restrict__ bsum, int n) {
    __shared__ int sh[SCAN_B];
    int t = threadIdx.x;
    int g = blockIdx.x * SCAN_B + t;
    int v = (g < n) ? in[g] : 0;
    sh[t] = v;
    __syncthreads();
    for (int d = 1; d < SCAN_B; d <<= 1) {
        int x = (t >= d) ? sh[t - d] : 0;
        __syncthreads();
        sh[t] += x;
        __syncthreads();
    }
    if (g < n) off[g] = sh[t] - v;
    if (t == SCAN_B - 1) bsum[blockIdx.x] = sh[t];
}

// --- 4b. exclusive scan of block sums (single block) ---
__global__ __launch_bounds__(SCAN_B) void scan2_kernel(int* __restrict__ bsum, int nb) {
    __shared__ int sh[SCAN_B];
    int t = threadIdx.x;
    int v = (t < nb) ? bsum[t] : 0;
    sh[t] = v;
    __syncthreads();
    for (int d = 1; d < SCAN_B; d <<= 1) {
        int x = (t >= d) ? sh[t - d] : 0;
        __syncthreads();
        sh[t] += x;
        __syncthreads();
    }
    if (t < nb) bsum[t] = sh[t] - v;
}

// --- 4c. add scanned block sums ---
__global__ void scanadd_kernel(int* __restrict__ data, const int* __restrict__ bsum, int n) {
    int i = blockIdx.x * blockDim.x + threadIdx.x;
    if (i < n) data[i] += bsum[i >> 10];          // SCAN_B == 1024
}

// --- 5. scatter edges into bucket-grouped colp via LDS cursors (no global atomics) ---
//     colp writes land in dense per-(bucket,slice) runs -> coalesced in L2.
__global__ void binscatter_kernel(const int* __restrict__ src, const int* __restrict__ dst,
                                  const int* __restrict__ offb, int* __restrict__ colp,
                                  int n_edges, int nb, int slice_len) {
    __shared__ int cur[NB_MAX];
    int s = blockIdx.x;
    for (int b = threadIdx.x; b < nb; b += blockDim.x)
        cur[b] = offb[(size_t)b * S_BIN + s];
    __syncthreads();
    int beg = s * slice_len;
    int end = beg + slice_len; if (end > n_edges) end = n_edges;
    for (int i = beg + threadIdx.x; i < end; i += blockDim.x) {
        int d = dst[i];
        int b = d >> BUCKET_BITS;
        int p = atomicAdd(&cur[b], 1);            // LDS atomic
        colp[p] = src[i] | ((d & (BUCKET_SZ - 1)) << 20);
    }
}

// --- 6. fp16 pre-scaled features: feat16 = (half)(feat * norm_l[row]) ---
__global__ void convert_kernel(const float* __restrict__ feat, const float* __restrict__ norm_l,
                               __half* __restrict__ feat16, int n_nodes) {
    int t = blockIdx.x * blockDim.x + threadIdx.x;
    int total = n_nodes * (D_FEAT / 8);
    if (t >= total) return;
    float nl = norm_l[t >> 4];                    // 16 threads per 128-elem row
    const float4* fp = (const float4*)feat + (size_t)t * 2;
    float4 a = fp[0], b = fp[1];
    __half2 h0 = __floats2half2_rn(a.x * nl, a.y * nl);
    __half2 h1 = __floats2half2_rn(a.z * nl, a.w * nl);
    __half2 h2 = __floats2half2_rn(b.x * nl, b.y * nl);
    __half2 h3 = __floats2half2_rn(b.z * nl, b.w * nl);
    uint4 o;
    o.x = *(unsigned int*)&h0; o.y = *(unsigned int*)&h1;
    o.z = *(unsigned int*)&h2; o.w = *(unsigned int*)&h3;
    ((uint4*)feat16)[t] = o;
}

// --- 7. bucket pull: one block per 128 dst nodes, LDS fp32 accumulators.
//     Per edge: coalesced 256B row gather + 2 ds_add_f32. In-degree counted in LDS. ---
__global__ __launch_bounds__(512) void pull_bucket_kernel(
        const __half* __restrict__ feat16, const int* __restrict__ colp,
        const int* __restrict__ offb, float* __restrict__ out,
        int n_nodes, int n_edges, int nb) {
    __shared__ float acc[BUCKET_SZ][D_FEAT];      // 64 KB
    __shared__ int cnt[BUCKET_SZ];
    int b = blockIdx.x;
    int tid = threadIdx.x;
    int node0 = b << BUCKET_BITS;
    int bn = n_nodes - node0; if (bn > BUCKET_SZ) bn = BUCKET_SZ;

    for (int i = tid; i < BUCKET_SZ * D_FEAT / 4; i += blockDim.x)
        ((f32x4*)acc)[i] = (f32x4){0.f, 0.f, 0.f, 0.f};
    if (tid < BUCKET_SZ) cnt[tid] = 0;
    __syncthreads();

    int beg = offb[(size_t)b * S_BIN];
    int end = (b + 1 < nb) ? offb[(size_t)(b + 1) * S_BIN] : n_edges;
    int lane = tid & 63, wv = tid >> 6;

    for (int base = beg + wv * 64; base < end; base += 512) {
        int m = end - base; if (m > 64) m = 64;
        int pk = (lane < m) ? colp[base + lane] : 0;   // coalesced edge chunk
        int k = 0;
        for (; k + 8 <= m; k += 8) {
            #pragma unroll
            for (int j = 0; j < 8; ++j) {
                int v = __shfl(pk, k + j, 64);
                int sid = v & 0xFFFFF;
                int lo = v >> 20;
                unsigned hv = ((const unsigned*)(feat16 + ((size_t)sid << 7)))[lane];
                float2 f = __half22float2(*(__half2*)&hv);
                atomicAdd(&acc[lo][lane * 2], f.x);
                atomicAdd(&acc[lo][lane * 2 + 1], f.y);
                if (lane == 0) atomicAdd(&cnt[lo], 1);
            }
        }
        for (; k < m; ++k) {
            int v = __shfl(pk, k, 64);
            int sid = v & 0xFFFFF;
            int lo = v >> 20;
            unsigned hv = ((const unsigned*)(feat16 + ((size_t)sid << 7)))[lane];
            float2 f = __half22float2(*(__half2*)&hv);
            atomicAdd(&acc[lo][lane * 2], f.x);
            atomicAdd(&acc[lo][lane * 2 + 1], f.y);
            if (lane == 0) atomicAdd(&cnt[lo], 1);
        }
    }
    __syncthreads();

    // epilogue: scale by rsqrt(max(deg_i,1)), stream out (write-once 51 MB)
    for (int i = tid; i < bn * (D_FEAT / 4); i += blockDim.x) {
        int row = i >> 5, q = i & 31;
        int c = cnt[row]; if (c < 1) c = 1;
        float nr = rsqrtf((float)c);
        f32x4 a = ((const f32x4*)&acc[row][0])[q];
        a.x *= nr; a.y *= nr; a.z *= nr; a.w *= nr;
        __builtin_nontemporal_store(a,
            (f32x4*)(out + (size_t)(node0 + row) * D_FEAT) + q);
    }
}

extern "C" void kernel_launch(void* const* d_in, const int* in_sizes, int n_in,
                              void* d_out, int out_size, void* d_ws, size_t ws_size,
                              hipStream_t stream) {
    const float* feat = (const float*)d_in[0];
    const int*   src  = (const int*)d_in[1];
    const int*   dst  = (const int*)d_in[2];
    float* out = (float*)d_out;

    const int n_nodes = in_sizes[0] / D_FEAT;            // 100000
    const int n_edges = in_sizes[1];                     // 1600000
    const int NR  = (n_nodes + HBINS - 1) / HBINS;       // 7
    const int nb  = (n_nodes + BUCKET_SZ - 1) / BUCKET_SZ; // 782 buckets
    const int N2  = nb * S_BIN;                          // 200192 scan elems
    const int sl_hist = (n_edges + HSLICES - 1) / HSLICES;
    const int sl_bin  = (n_edges + S_BIN - 1) / S_BIN;

    // ws: [A: part_o (25.6MB) overlaid by feat16 (25.6MB)] norm_l partb offb bsum colp  ~34MB
    char* basep = (char*)d_ws;
    size_t partA = (size_t)HSLICES * n_nodes * sizeof(int);
    size_t f16A  = (size_t)n_nodes * D_FEAT * sizeof(__half);
    size_t regA  = partA > f16A ? partA : f16A;
    int*    part_o = (int*)basep;
    __half* feat16 = (__half*)basep;                     // written after merge
    float*  norm_l = (float*)(basep + regA);
    int*    partb  = (int*)(norm_l + n_nodes);
    int*    offb   = partb + N2;
    int*    bsum   = offb + N2;
    int*    colp   = bsum + SCAN_B;

    // 1-2: out-degree -> norm_l (LDS histogram, no global atomics)
    hist_kernel<<<HSLICES * NR, 256, 0, stream>>>(src, part_o, n_edges, n_nodes, sl_hist);
    merge_kernel<<<(n_nodes + 255) / 256, 256, 0, stream>>>(part_o, norm_l, n_nodes);

    // 3-4: bucket-bin histogram + flat exclusive scan -> per-(bucket,slice) offsets
    binhist_kernel<<<S_BIN, 256, 0, stream>>>(dst, partb, n_edges, nb, sl_bin);
    {
        int nsb = (N2 + SCAN_B - 1) / SCAN_B;            // 196 <= 1024
        scan1_kernel<<<nsb, SCAN_B, 0, stream>>>(partb, offb, bsum, N2);
        scan2_kernel<<<1, SCAN_B, 0, stream>>>(bsum, nsb);
        scanadd_kernel<<<(N2 + 255) / 256, 256, 0, stream>>>(offb, bsum, N2);
    }

    // 5: bucket-grouped edge list (LDS cursors, coalesced writes)
    binscatter_kernel<<<S_BIN, 256, 0, stream>>>(src, dst, offb, colp, n_edges, nb, sl_bin);

    // 6: fp16 pre-scaled features (overwrites part_o region)
    {
        int total = n_nodes * (D_FEAT / 8);
        convert_kernel<<<(total + 255) / 256, 256, 0, stream>>>(feat, norm_l, feat16, n_nodes);
    }

    // 7: pull with LDS accumulation; in-degree counted in LDS
    pull_bucket_kernel<<<nb, 512, 0, stream>>>(feat16, colp, offb, out, n_nodes, n_edges, nb);
}

// Round 3
// 239.125 us; speedup vs baseline: 6.4769x; 6.4769x over previous
//
#include <hip/hip_runtime.h>
#include <hip/hip_fp16.h>

#define D_FEAT      128
#define SCAN_B      1024
#define S_BIN       256      // edge slices for binning passes
#define BUCKET_BITS 7
#define BUCKET_SZ   128      // nodes per bucket
#define NB_MAX      1024     // max buckets (131072 nodes)
#define SORT_CAP    6144     // LDS edge buffer per bucket (mean 2048, sigma 45)

typedef float f32x2 __attribute__((ext_vector_type(2)));

// --- 1. fused per-slice bucket histograms of dst AND src (LDS only, no global atomics) ---
__global__ void binhist2_kernel(const int* __restrict__ src, const int* __restrict__ dst,
                                int* __restrict__ part2, int n_edges, int nb, int N2,
                                int slice_len) {
    __shared__ int hd[NB_MAX];
    __shared__ int hs[NB_MAX];
    int s = blockIdx.x;
    for (int i = threadIdx.x; i < nb; i += blockDim.x) { hd[i] = 0; hs[i] = 0; }
    __syncthreads();
    int beg = s * slice_len;
    int end = beg + slice_len; if (end > n_edges) end = n_edges;
    for (int i = beg + threadIdx.x; i < end; i += blockDim.x) {
        atomicAdd(&hd[dst[i] >> BUCKET_BITS], 1);
        atomicAdd(&hs[src[i] >> BUCKET_BITS], 1);
    }
    __syncthreads();
    for (int b = threadIdx.x; b < nb; b += blockDim.x) {
        part2[(size_t)b * S_BIN + s] = hd[b];                  // dst half
        part2[(size_t)(N2 + b * S_BIN) + s] = hs[b];           // src half
    }
}

// --- 2a. per-block exclusive scan, block totals to bsum ---
__global__ __launch_bounds__(SCAN_B) void scan1_kernel(const int* __restrict__ in,
        int* __restrict__ off, int* __restrict__ bsum, int n) {
    __shared__ int sh[SCAN_B];
    int t = threadIdx.x;
    int g = blockIdx.x * SCAN_B + t;
    int v = (g < n) ? in[g] : 0;
    sh[t] = v;
    __syncthreads();
    for (int d = 1; d < SCAN_B; d <<= 1) {
        int x = (t >= d) ? sh[t - d] : 0;
        __syncthreads();
        sh[t] += x;
        __syncthreads();
    }
    if (g < n) off[g] = sh[t] - v;
    if (t == SCAN_B - 1) bsum[blockIdx.x] = sh[t];
}

// --- 2b. exclusive scan of block sums (single block) ---
__global__ __launch_bounds__(SCAN_B) void scan2_kernel(int* __restrict__ bsum, int nb) {
    __shared__ int sh[SCAN_B];
    int t = threadIdx.x;
    int v = (t < nb) ? bsum[t] : 0;
    sh[t] = v;
    __syncthreads();
    for (int d = 1; d < SCAN_B; d <<= 1) {
        int x = (t >= d) ? sh[t - d] : 0;
        __syncthreads();
        sh[t] += x;
        __syncthreads();
    }
    if (t < nb) bsum[t] = sh[t] - v;
}

// --- 2c. add scanned block sums ---
__global__ void scanadd_kernel(int* __restrict__ data, const int* __restrict__ bsum, int n) {
    int i = blockIdx.x * blockDim.x + threadIdx.x;
    if (i < n) data[i] += bsum[i >> 10];          // SCAN_B == 1024
}

// --- 3. scatter edges into bucket-grouped streams via LDS cursors (no global atomics).
//        colp: dst-bucketed, packs src | (dst&127)<<20.  colp_src: src-bucketed, src&127 bytes. ---
__global__ void binscatter2_kernel(const int* __restrict__ src, const int* __restrict__ dst,
                                   const int* __restrict__ offb, int* __restrict__ colp,
                                   unsigned char* __restrict__ colp_src,
                                   int n_edges, int nb, int N2, int slice_len) {
    __shared__ int cd[NB_MAX];
    __shared__ int cs[NB_MAX];
    int s = blockIdx.x;
    for (int b = threadIdx.x; b < nb; b += blockDim.x) {
        cd[b] = offb[(size_t)b * S_BIN + s];
        cs[b] = offb[(size_t)(N2 + b * S_BIN) + s] - n_edges;  // src half rebased
    }
    __syncthreads();
    int beg = s * slice_len;
    int end = beg + slice_len; if (end > n_edges) end = n_edges;
    for (int i = beg + threadIdx.x; i < end; i += blockDim.x) {
        int d = dst[i], sv = src[i];
        int pD = atomicAdd(&cd[d >> BUCKET_BITS], 1);          // LDS int atomic (native)
        colp[pD] = sv | ((d & (BUCKET_SZ - 1)) << 20);
        int pS = atomicAdd(&cs[sv >> BUCKET_BITS], 1);
        colp_src[pS] = (unsigned char)(sv & (BUCKET_SZ - 1));
    }
}

// --- 4. in-bucket counting sort (in place) -> per-node CSR offsets. Int LDS atomics only. ---
__global__ __launch_bounds__(256) void sortbucket_kernel(
        int* __restrict__ colp, const int* __restrict__ offb,
        int* __restrict__ node_off, int n_nodes, int n_edges, int nb) {
    __shared__ int buf[SORT_CAP];
    __shared__ int cnt[BUCKET_SZ];
    __shared__ int sa[BUCKET_SZ];
    __shared__ int sb[BUCKET_SZ];
    int b = blockIdx.x, tid = threadIdx.x;
    int beg = offb[(size_t)b * S_BIN];
    int end = (b + 1 < nb) ? offb[(size_t)(b + 1) * S_BIN] : n_edges;
    int m = end - beg;                                         // ~2048, < SORT_CAP
    if (tid < BUCKET_SZ) cnt[tid] = 0;
    __syncthreads();
    for (int i = tid; i < m; i += blockDim.x) {
        int v = colp[beg + i];
        if (i < SORT_CAP) buf[i] = v;
        atomicAdd(&cnt[(v >> 20) & (BUCKET_SZ - 1)], 1);
    }
    __syncthreads();
    // inclusive scan of cnt via ping-pong
    int* rp = sa; int* wp = sb;
    if (tid < BUCKET_SZ) sa[tid] = cnt[tid];
    __syncthreads();
    for (int d = 1; d < BUCKET_SZ; d <<= 1) {
        if (tid < BUCKET_SZ) wp[tid] = rp[tid] + (tid >= d ? rp[tid - d] : 0);
        __syncthreads();
        int* t = rp; rp = wp; wp = t;
    }
    int node0 = b << BUCKET_BITS;
    int bn = n_nodes - node0; if (bn > BUCKET_SZ) bn = BUCKET_SZ;
    if (tid < BUCKET_SZ) {
        int ex = rp[tid] - cnt[tid];                           // exclusive
        wp[tid] = ex;                                          // cursors
        if (tid < bn) node_off[node0 + tid] = beg + ex;
    }
    if (b == nb - 1 && tid == 0) node_off[n_nodes] = end;      // global sentinel
    __syncthreads();
    int mm = m < SORT_CAP ? m : SORT_CAP;
    for (int i = tid; i < mm; i += blockDim.x) {
        int v = buf[i];
        int p = atomicAdd(&wp[(v >> 20) & (BUCKET_SZ - 1)], 1);
        colp[beg + p] = v & 0xFFFFF;                           // src only (17 bits)
    }
}

// --- 5. per-bucket out-degree count -> norm_l = rsqrt(max(deg_o,1)) ---
__global__ void countsrc_kernel(const unsigned char* __restrict__ colp_src,
                                const int* __restrict__ offb, float* __restrict__ norm_l,
                                int n_nodes, int n_edges, int nb, int N2) {
    __shared__ int cnt[BUCKET_SZ];
    int b = blockIdx.x, tid = threadIdx.x;
    int beg = offb[(size_t)(N2 + b * S_BIN)] - n_edges;
    int end = (b + 1 < nb) ? offb[(size_t)(N2 + (b + 1) * S_BIN)] - n_edges : n_edges;
    if (tid < BUCKET_SZ) cnt[tid] = 0;
    __syncthreads();
    for (int i = beg + tid; i < end; i += blockDim.x)
        atomicAdd(&cnt[colp_src[i]], 1);
    __syncthreads();
    int node0 = b << BUCKET_BITS;
    int bn = n_nodes - node0; if (bn > BUCKET_SZ) bn = BUCKET_SZ;
    if (tid < bn) {
        int c = cnt[tid]; if (c < 1) c = 1;
        norm_l[node0 + tid] = rsqrtf((float)c);
    }
}

// --- 6. fp16 pre-scaled features: feat16 = (half)(feat * norm_l[row]) ---
__global__ void convert_kernel(const float* __restrict__ feat, const float* __restrict__ norm_l,
                               __half* __restrict__ feat16, int n_nodes) {
    int t = blockIdx.x * blockDim.x + threadIdx.x;
    int total = n_nodes * (D_FEAT / 8);
    if (t >= total) return;
    float nl = norm_l[t >> 4];                    // 16 threads per 128-elem row
    const float4* fp = (const float4*)feat + (size_t)t * 2;
    float4 a = fp[0], b = fp[1];
    __half2 h0 = __floats2half2_rn(a.x * nl, a.y * nl);
    __half2 h1 = __floats2half2_rn(a.z * nl, a.w * nl);
    __half2 h2 = __floats2half2_rn(b.x * nl, b.y * nl);
    __half2 h3 = __floats2half2_rn(b.z * nl, b.w * nl);
    uint4 o;
    o.x = *(unsigned int*)&h0; o.y = *(unsigned int*)&h1;
    o.z = *(unsigned int*)&h2; o.w = *(unsigned int*)&h3;
    ((uint4*)feat16)[t] = o;
}

// --- 7. CSR pull: one wave per dst node, coalesced index chunks, 8 gathers in flight,
//        register fp32 accumulation, zero atomics. deg_i = e - s for free. ---
__global__ __launch_bounds__(256) void pull_csr_kernel(
        const __half* __restrict__ feat16, const int* __restrict__ col,
        const int* __restrict__ node_off, float* __restrict__ out, int n_nodes) {
    int wid  = (int)(((long long)blockIdx.x * blockDim.x + threadIdx.x) >> 6);
    int lane = threadIdx.x & 63;
    if (wid >= n_nodes) return;
    int s = __builtin_amdgcn_readfirstlane(node_off[wid]);
    int e = __builtin_amdgcn_readfirstlane(node_off[wid + 1]);
    float accx = 0.f, accy = 0.f;
    const __half2* lrow = (const __half2*)feat16 + lane;   // lane's 4B slot in any row

    for (int base = s; base < e; base += 64) {
        int m = e - base; if (m > 64) m = 64;
        int cv = (lane < m) ? col[base + lane] : 0;        // coalesced index chunk
        int k = 0;
        for (; k + 8 <= m; k += 8) {
            #pragma unroll
            for (int j = 0; j < 8; ++j) {
                int idx = __shfl(cv, k + j, 64);
                __half2 h = lrow[(size_t)(unsigned)idx << 6];   // idx*256 B row
                float2 f = __half22float2(h);
                accx += f.x; accy += f.y;
            }
        }
        for (; k < m; ++k) {
            int idx = __shfl(cv, k, 64);
            __half2 h = lrow[(size_t)(unsigned)idx << 6];
            float2 f = __half22float2(h);
            accx += f.x; accy += f.y;
        }
    }

    int cnt = e - s; if (cnt < 1) cnt = 1;
    float nr = rsqrtf((float)cnt);
    f32x2 r; r.x = accx * nr; r.y = accy * nr;
    __builtin_nontemporal_store(r, (f32x2*)(out + (size_t)wid * D_FEAT) + lane);
}

extern "C" void kernel_launch(void* const* d_in, const int* in_sizes, int n_in,
                              void* d_out, int out_size, void* d_ws, size_t ws_size,
                              hipStream_t stream) {
    const float* feat = (const float*)d_in[0];
    const int*   src  = (const int*)d_in[1];
    const int*   dst  = (const int*)d_in[2];
    float* out = (float*)d_out;

    const int n_nodes = in_sizes[0] / D_FEAT;                 // 100000
    const int n_edges = in_sizes[1];                          // 1600000
    const int nb = (n_nodes + BUCKET_SZ - 1) / BUCKET_SZ;     // 782
    const int N2 = nb * S_BIN;                                // 200192 per half
    const int NSCAN = 2 * N2;                                 // 400384
    const int sl = (n_edges + S_BIN - 1) / S_BIN;             // 6250

    // ws (~37.6 MB): node_off norm_l part2 offb bsum colp colp_src feat16
    auto alignup = [](size_t x) { return (x + 255) & ~(size_t)255; };
    char* p = (char*)d_ws;
    int*    node_off = (int*)p;            p += alignup((size_t)(n_nodes + 1) * 4);
    float*  norm_l   = (float*)p;          p += alignup((size_t)n_nodes * 4);
    int*    part2    = (int*)p;            p += alignup((size_t)NSCAN * 4);
    int*    offb     = (int*)p;            p += alignup((size_t)NSCAN * 4);
    int*    bsum     = (int*)p;            p += alignup((size_t)SCAN_B * 4);
    int*    colp     = (int*)p;            p += alignup((size_t)n_edges * 4);
    unsigned char* colp_src = (unsigned char*)p; p += alignup((size_t)n_edges);
    __half* feat16   = (__half*)p;

    // 1. fused bucket histograms (dst + src)
    binhist2_kernel<<<S_BIN, 256, 0, stream>>>(src, dst, part2, n_edges, nb, N2, sl);

    // 2. one flat exclusive scan over both halves
    {
        int nsb = (NSCAN + SCAN_B - 1) / SCAN_B;              // 391
        scan1_kernel<<<nsb, SCAN_B, 0, stream>>>(part2, offb, bsum, NSCAN);
        scan2_kernel<<<1, SCAN_B, 0, stream>>>(bsum, nsb);
        scanadd_kernel<<<(NSCAN + 255) / 256, 256, 0, stream>>>(offb, bsum, NSCAN);
    }

    // 3. bucket-grouped edge streams (LDS cursors, coalesced-ish writes)
    binscatter2_kernel<<<S_BIN, 256, 0, stream>>>(src, dst, offb, colp, colp_src,
                                                  n_edges, nb, N2, sl);

    // 4. in-bucket counting sort -> per-node CSR (in place) + node_off
    sortbucket_kernel<<<nb, 256, 0, stream>>>(colp, offb, node_off, n_nodes, n_edges, nb);

    // 5. out-degree -> norm_l
    countsrc_kernel<<<nb, 256, 0, stream>>>(colp_src, offb, norm_l, n_nodes, n_edges, nb, N2);

    // 6. fp16 pre-scaled features
    {
        int total = n_nodes * (D_FEAT / 8);
        convert_kernel<<<(total + 255) / 256, 256, 0, stream>>>(feat, norm_l, feat16, n_nodes);
    }

    // 7. pull
    {
        long long total = (long long)n_nodes * 64;
        pull_csr_kernel<<<(int)((total + 255) / 256), 256, 0, stream>>>(feat16, colp, node_off,
                                                                        out, n_nodes);
    }
}